// Round 5
// baseline (46.873 us; speedup 1.0000x reference)
//
#include <hip/hip_runtime.h>
#include <hip/hip_bf16.h>

// out[i] = sigmoid(row_avg[i] * w + b), N = 33554432 fp32.
// Memory/latency-bound streaming. Temporal loads (L3-resident input across
// replays), nontemporal stores, 4x unroll for memory-level parallelism:
// 4 independent 16B loads in flight per thread before compute/store.

typedef float floatx4 __attribute__((ext_vector_type(4)));

__global__ void __launch_bounds__(256) sigmoid_linear_kernel(
    const float* __restrict__ x, const float* __restrict__ wp,
    const float* __restrict__ bp, float* __restrict__ out, int n4) {
    const float w = wp[0];
    const float b = bp[0];
    const floatx4* __restrict__ x4 = reinterpret_cast<const floatx4*>(x);
    floatx4* __restrict__ o4 = reinterpret_cast<floatx4*>(out);

    const int tid = blockIdx.x * blockDim.x + threadIdx.x;
    const int stride = gridDim.x * blockDim.x;

    int i = tid;
    // 4x unrolled: issue 4 independent loads before any compute/store.
    for (; i + 3 * stride < n4; i += 4 * stride) {
        floatx4 v0 = x4[i];
        floatx4 v1 = x4[i + stride];
        floatx4 v2 = x4[i + 2 * stride];
        floatx4 v3 = x4[i + 3 * stride];
        floatx4 r0, r1, r2, r3;
        #pragma unroll
        for (int j = 0; j < 4; ++j) {
            r0[j] = 1.0f / (1.0f + __expf(-(v0[j] * w + b)));
            r1[j] = 1.0f / (1.0f + __expf(-(v1[j] * w + b)));
            r2[j] = 1.0f / (1.0f + __expf(-(v2[j] * w + b)));
            r3[j] = 1.0f / (1.0f + __expf(-(v3[j] * w + b)));
        }
        __builtin_nontemporal_store(r0, &o4[i]);
        __builtin_nontemporal_store(r1, &o4[i + stride]);
        __builtin_nontemporal_store(r2, &o4[i + 2 * stride]);
        __builtin_nontemporal_store(r3, &o4[i + 3 * stride]);
    }
    for (; i < n4; i += stride) {
        floatx4 v = x4[i];
        floatx4 r;
        #pragma unroll
        for (int j = 0; j < 4; ++j)
            r[j] = 1.0f / (1.0f + __expf(-(v[j] * w + b)));
        __builtin_nontemporal_store(r, &o4[i]);
    }
}

extern "C" void kernel_launch(void* const* d_in, const int* in_sizes, int n_in,
                              void* d_out, int out_size, void* d_ws, size_t ws_size,
                              hipStream_t stream) {
    const float* x = (const float*)d_in[0];   // row_avg, [1, N] fp32
    const float* w = (const float*)d_in[1];   // [1,1]
    const float* b = (const float*)d_in[2];   // [1]
    float* out = (float*)d_out;               // [N] fp32

    const int n = in_sizes[0];                // 33554432
    const int n4 = n >> 2;

    const int block = 256;
    int grid = (n4 + block - 1) / block;
    if (grid > 2048) grid = 2048;

    sigmoid_linear_kernel<<<grid, block, 0, stream>>>(x, w, b, out, n4);
}

// Round 6
// 42.253 us; speedup vs baseline: 1.1093x; 1.1093x over previous
//
#include <hip/hip_runtime.h>
#include <hip/hip_bf16.h>

// out[i] = sigmoid(row_avg[i] * w + b), N = 33554432 fp32.
// Streaming, memory-bound. Full grid: one float4 per thread, no loop.
// 32768 blocks x 256 threads x 4 floats = 33554432 exactly.

typedef float floatx4 __attribute__((ext_vector_type(4)));

__global__ void __launch_bounds__(256) sigmoid_linear_kernel(
    const float* __restrict__ x, const float* __restrict__ wp,
    const float* __restrict__ bp, float* __restrict__ out, int n4) {
    const float w = wp[0];
    const float b = bp[0];
    const floatx4* __restrict__ x4 = reinterpret_cast<const floatx4*>(x);
    floatx4* __restrict__ o4 = reinterpret_cast<floatx4*>(out);

    const int i = blockIdx.x * blockDim.x + threadIdx.x;
    if (i < n4) {
        floatx4 v = x4[i];
        floatx4 r;
        #pragma unroll
        for (int j = 0; j < 4; ++j)
            r[j] = 1.0f / (1.0f + __expf(-(v[j] * w + b)));
        o4[i] = r;
    }
}

extern "C" void kernel_launch(void* const* d_in, const int* in_sizes, int n_in,
                              void* d_out, int out_size, void* d_ws, size_t ws_size,
                              hipStream_t stream) {
    const float* x = (const float*)d_in[0];   // row_avg, [1, N] fp32
    const float* w = (const float*)d_in[1];   // [1,1]
    const float* b = (const float*)d_in[2];   // [1]
    float* out = (float*)d_out;               // [N] fp32

    const int n = in_sizes[0];                // 33554432
    const int n4 = n >> 2;                    // 8388608

    const int block = 256;
    const int grid = (n4 + block - 1) / block;  // 32768

    sigmoid_linear_kernel<<<grid, block, 0, stream>>>(x, w, b, out, n4);
}